// Round 1
// baseline (119.395 us; speedup 1.0000x reference)
//
#include <hip/hip_runtime.h>

#define B_ROWS   32768
#define NUM_CLS  1000
#define FEAT     512

// ws layout (floats):
//   [0]            intra-distance sum
//   [1]            count of class C-2
//   [2]            count of class C-1
//   [64 .. 576)    feature sums for class C-2
//   [576 .. 1088)  feature sums for class C-1
#define WS_INTRA  0
#define WS_CNT0   1
#define WS_CNT1   2
#define WS_SUM0   64
#define WS_SUM1   (64 + 512)
#define WS_FLOATS (64 + 1024)

__global__ __launch_bounds__(256) void loss_pass1(
    const float* __restrict__ features,
    const int*   __restrict__ labels,
    const float* __restrict__ center,
    float*       __restrict__ ws)
{
    const int wave = threadIdx.x >> 6;
    const int lane = threadIdx.x & 63;
    const int row  = blockIdx.x * 4 + wave;   // grid = B/4 exactly

    const int lab = labels[row];

    const float4* frow = (const float4*)(features + (size_t)row * FEAT);
    const float4* crow = (const float4*)(center   + (size_t)lab * FEAT);

    // 64 lanes * 2 float4 = 512 floats, fully coalesced
    float4 f0 = frow[lane];
    float4 f1 = frow[lane + 64];
    float4 c0 = crow[lane];
    float4 c1 = crow[lane + 64];

    float dx0 = f0.x - c0.x, dy0 = f0.y - c0.y, dz0 = f0.z - c0.z, dw0 = f0.w - c0.w;
    float dx1 = f1.x - c1.x, dy1 = f1.y - c1.y, dz1 = f1.z - c1.z, dw1 = f1.w - c1.w;

    float p = dx0*dx0 + dy0*dy0 + dz0*dz0 + dw0*dw0
            + dx1*dx1 + dy1*dy1 + dz1*dz1 + dw1*dw1;

    // 64-lane butterfly reduce
    #pragma unroll
    for (int off = 32; off; off >>= 1)
        p += __shfl_xor(p, off);

    __shared__ float s[4];
    if (lane == 0) {
        float dist = sqrtf(p);
        dist = fminf(fmaxf(dist, 1e-12f), 1e12f);
        s[wave] = dist;
    }

    // Inter-loss bookkeeping: only classes C-2, C-1 matter (~65 rows total)
    if (lab >= NUM_CLS - 2) {
        float* sums = ws + (lab == NUM_CLS - 2 ? WS_SUM0 : WS_SUM1);
        const int base = lane * 4;
        atomicAdd(&sums[base + 0],   f0.x);
        atomicAdd(&sums[base + 1],   f0.y);
        atomicAdd(&sums[base + 2],   f0.z);
        atomicAdd(&sums[base + 3],   f0.w);
        atomicAdd(&sums[base + 256], f1.x);
        atomicAdd(&sums[base + 257], f1.y);
        atomicAdd(&sums[base + 258], f1.z);
        atomicAdd(&sums[base + 259], f1.w);
        if (lane == 0)
            atomicAdd(&ws[lab == NUM_CLS - 2 ? WS_CNT0 : WS_CNT1], 1.0f);
    }

    __syncthreads();
    if (threadIdx.x == 0)
        atomicAdd(&ws[WS_INTRA], s[0] + s[1] + s[2] + s[3]);
}

__global__ __launch_bounds__(256) void loss_pass2(
    const float* __restrict__ center,
    const float* __restrict__ ws,
    float*       __restrict__ out)
{
    const int t = threadIdx.x;           // 256 threads, 2 dims each
    const float cnt0 = fmaxf(ws[WS_CNT0], 1.0f);
    const float cnt1 = fmaxf(ws[WS_CNT1], 1.0f);

    float p = 0.0f;
    #pragma unroll
    for (int k = 0; k < 2; ++k) {
        const int d = t * 2 + k;
        float a = (center[(size_t)(NUM_CLS - 2) * FEAT + d] + ws[WS_SUM0 + d]) / cnt0;
        float b = (center[(size_t)(NUM_CLS - 1) * FEAT + d] + ws[WS_SUM1 + d]) / cnt1;
        float df = a - b;
        p += df * df;
    }

    #pragma unroll
    for (int off = 32; off; off >>= 1)
        p += __shfl_xor(p, off);

    __shared__ float s[4];
    if ((t & 63) == 0) s[t >> 6] = p;
    __syncthreads();

    if (t == 0) {
        float d_last = sqrtf(s[0] + s[1] + s[2] + s[3]);
        out[0] = ws[WS_INTRA] * (1.0f / (float)B_ROWS);
        out[1] = (2.0f / d_last) * (1.0f / ((float)NUM_CLS * (float)(NUM_CLS - 1)));
    }
}

extern "C" void kernel_launch(void* const* d_in, const int* in_sizes, int n_in,
                              void* d_out, int out_size, void* d_ws, size_t ws_size,
                              hipStream_t stream) {
    const float* features = (const float*)d_in[0];
    const int*   labels   = (const int*)d_in[1];
    const float* center   = (const float*)d_in[2];
    float* out = (float*)d_out;
    float* ws  = (float*)d_ws;

    hipMemsetAsync(ws, 0, WS_FLOATS * sizeof(float), stream);

    loss_pass1<<<B_ROWS / 4, 256, 0, stream>>>(features, labels, center, ws);
    loss_pass2<<<1, 256, 0, stream>>>(center, ws, out);
}

// Round 2
// 27.303 us; speedup vs baseline: 4.3730x; 4.3730x over previous
//
#include <hip/hip_runtime.h>

#define B_ROWS   32768
#define NUM_CLS  1000
#define FEAT     512

#define BLOCKS          1024
#define WAVES_PER_BLOCK 4
#define TOTAL_WAVES     (BLOCKS * WAVES_PER_BLOCK)     // 4096
#define ROWS_PER_WAVE   (B_ROWS / TOTAL_WAVES)         // 8

// ws layout (floats):
//   [1]              count of class C-2
//   [2]              count of class C-1
//   [64 .. 576)      feature sums for class C-2
//   [576 .. 1088)    feature sums for class C-1
//   [1088 .. 2112)   per-block intra partial sums (written unconditionally)
#define WS_CNT0   1
#define WS_CNT1   2
#define WS_SUM0   64
#define WS_SUM1   (64 + 512)
#define WS_PART   (64 + 1024)
#define WS_ZERO_FLOATS (64 + 1024)   // only counts+sums need zeroing

__global__ __launch_bounds__(256) void loss_pass1(
    const float* __restrict__ features,
    const int*   __restrict__ labels,
    const float* __restrict__ center,
    float*       __restrict__ ws)
{
    const int wave = threadIdx.x >> 6;
    const int lane = threadIdx.x & 63;
    const int wid  = blockIdx.x * WAVES_PER_BLOCK + wave;
    const int base_row = wid * ROWS_PER_WAVE;

    // Prefetch this wave's 8 labels into lanes 0..7 (replicated across lanes 8..63)
    const int mylab = labels[base_row + (lane & 7)];

    float acc = 0.0f;

    #pragma unroll 2
    for (int r = 0; r < ROWS_PER_WAVE; ++r) {
        const int row = base_row + r;
        const int lab = __shfl(mylab, r);

        const float4* frow = (const float4*)(features + (size_t)row * FEAT);
        const float4* crow = (const float4*)(center   + (size_t)lab * FEAT);

        float4 f0 = frow[lane];
        float4 f1 = frow[lane + 64];
        float4 c0 = crow[lane];
        float4 c1 = crow[lane + 64];

        float dx0 = f0.x - c0.x, dy0 = f0.y - c0.y, dz0 = f0.z - c0.z, dw0 = f0.w - c0.w;
        float dx1 = f1.x - c1.x, dy1 = f1.y - c1.y, dz1 = f1.z - c1.z, dw1 = f1.w - c1.w;

        float p = dx0*dx0 + dy0*dy0 + dz0*dz0 + dw0*dw0
                + dx1*dx1 + dy1*dy1 + dz1*dz1 + dw1*dw1;

        #pragma unroll
        for (int off = 32; off; off >>= 1)
            p += __shfl_xor(p, off);

        if (lane == 0) {
            float dist = sqrtf(p);
            acc += fminf(fmaxf(dist, 1e-12f), 1e12f);
        }

        // Inter-loss bookkeeping: only classes C-2, C-1 matter (~65 rows of 32768)
        if (lab >= NUM_CLS - 2) {
            float* sums = ws + (lab == NUM_CLS - 2 ? WS_SUM0 : WS_SUM1);
            const int base = lane * 4;
            atomicAdd(&sums[base + 0],   f0.x);
            atomicAdd(&sums[base + 1],   f0.y);
            atomicAdd(&sums[base + 2],   f0.z);
            atomicAdd(&sums[base + 3],   f0.w);
            atomicAdd(&sums[base + 256], f1.x);
            atomicAdd(&sums[base + 257], f1.y);
            atomicAdd(&sums[base + 258], f1.z);
            atomicAdd(&sums[base + 259], f1.w);
            if (lane == 0)
                atomicAdd(&ws[lab == NUM_CLS - 2 ? WS_CNT0 : WS_CNT1], 1.0f);
        }
    }

    __shared__ float s[WAVES_PER_BLOCK];
    if (lane == 0) s[wave] = acc;
    __syncthreads();
    if (threadIdx.x == 0)
        ws[WS_PART + blockIdx.x] = s[0] + s[1] + s[2] + s[3];  // unique slot: no atomics
}

__global__ __launch_bounds__(256) void loss_pass2(
    const float* __restrict__ center,
    const float* __restrict__ ws,
    float*       __restrict__ out)
{
    const int t = threadIdx.x;
    const float cnt0 = fmaxf(ws[WS_CNT0], 1.0f);
    const float cnt1 = fmaxf(ws[WS_CNT1], 1.0f);

    // inter: 512 dims over 256 threads (2 each)
    float p_inter = 0.0f;
    #pragma unroll
    for (int k = 0; k < 2; ++k) {
        const int d = t * 2 + k;
        float a = (center[(size_t)(NUM_CLS - 2) * FEAT + d] + ws[WS_SUM0 + d]) / cnt0;
        float b = (center[(size_t)(NUM_CLS - 1) * FEAT + d] + ws[WS_SUM1 + d]) / cnt1;
        float df = a - b;
        p_inter += df * df;
    }

    // intra: sum 1024 block partials, 4 per thread
    float p_intra = ws[WS_PART + t] + ws[WS_PART + t + 256]
                  + ws[WS_PART + t + 512] + ws[WS_PART + t + 768];

    #pragma unroll
    for (int off = 32; off; off >>= 1) {
        p_inter += __shfl_xor(p_inter, off);
        p_intra += __shfl_xor(p_intra, off);
    }

    __shared__ float si[4], sa[4];
    if ((t & 63) == 0) { si[t >> 6] = p_inter; sa[t >> 6] = p_intra; }
    __syncthreads();

    if (t == 0) {
        float d_last = sqrtf(si[0] + si[1] + si[2] + si[3]);
        out[0] = (sa[0] + sa[1] + sa[2] + sa[3]) * (1.0f / (float)B_ROWS);
        out[1] = (2.0f / d_last) * (1.0f / ((float)NUM_CLS * (float)(NUM_CLS - 1)));
    }
}

extern "C" void kernel_launch(void* const* d_in, const int* in_sizes, int n_in,
                              void* d_out, int out_size, void* d_ws, size_t ws_size,
                              hipStream_t stream) {
    const float* features = (const float*)d_in[0];
    const int*   labels   = (const int*)d_in[1];
    const float* center   = (const float*)d_in[2];
    float* out = (float*)d_out;
    float* ws  = (float*)d_ws;

    hipMemsetAsync(ws, 0, WS_ZERO_FLOATS * sizeof(float), stream);

    loss_pass1<<<BLOCKS, 256, 0, stream>>>(features, labels, center, ws);
    loss_pass2<<<1, 256, 0, stream>>>(center, ws, out);
}